// Round 2
// baseline (185.358 us; speedup 1.0000x reference)
//
#include <hip/hip_runtime.h>
#include <cstdint>
#include <cstddef>

// Problem constants (B, S, E, H, MAXLEN) = (2, 2048, 1024, 16, 2048)
constexpr int Sn = 2048;
constexpr int En = 1024;
constexpr int Bn = 2;
constexpr int Hn = 16;
constexpr int CHUNK = 32;          // 32-row chunks (2 per wave tile)
constexpr int NCH = Sn / CHUNK;    // 64 chunks per batch
constexpr int Mtot = Bn * Sn;      // 4096
constexpr int GCH = Mtot / CHUNK;  // 128 global chunks

typedef __bf16 bf16x8 __attribute__((ext_vector_type(8)));
typedef float  f32x4  __attribute__((ext_vector_type(4)));

__device__ __forceinline__ unsigned short f2bf(float f) {
    union { float f; uint32_t u; } v; v.f = f;
    const uint32_t u = v.u;
    return (unsigned short)((u + 0x7fffu + ((u >> 16) & 1u)) >> 16);  // RNE
}
__device__ __forceinline__ float bf2f(unsigned short s) {
    union { uint32_t u; float f; } v; v.u = (uint32_t)s << 16; return v.f;
}

// Pack 8 fp32 -> 8 bf16 (one uint4) via native cvt (RNE on gfx950; compiler
// emits v_cvt_pk_bf16_f32 pairs — do NOT hand-write asm cvt_pk, m240).
__device__ __forceinline__ uint4 pack8(float4 lo, float4 hi) {
    bf16x8 r;
    r[0] = (__bf16)lo.x; r[1] = (__bf16)lo.y; r[2] = (__bf16)lo.z; r[3] = (__bf16)lo.w;
    r[4] = (__bf16)hi.x; r[5] = (__bf16)hi.y; r[6] = (__bf16)hi.z; r[7] = (__bf16)hi.w;
    return *(uint4*)&r;
}

// ---------------------------------------------------------------------------
// Shared GEMM geometry (R8/R13 structure, unchanged):
// C[m,n] = sum_k A[m,k]*W[n,k] + bias[n].
// Tile 128(M) x 64(N), BK=64, 256 threads = 4 waves in 2x2, wave tile 64x32.
// LDS: 1024 B chunk = 16 rows x 32 k in fragment order, lane l -> slot
// l*16 B (conflict-free b128). XCD swizzle: xcd = id&7 owns 4 contiguous
// row-blocks. 2-deep p/q register staging (R14's 3-deep was NEUTRAL ->
// staging-load latency is NOT the phase cost; reverted).
// R15: gemm1 stages DIRECTLY from fp32 (x, Wv) and converts to bf16 in
// registers before ds_write — the cast2 dispatch is eliminated. LDS layout,
// K-loop and MFMA path are byte-identical to the bf16-staged variant.
// ---------------------------------------------------------------------------

#define COMPUTE()                                                                              \
    {                                                                                          \
        bf16x8 af[4][2], bfr[2][2];                                                            \
        _Pragma("unroll")                                                                      \
        for (int i = 0; i < 4; ++i)                                                            \
            _Pragma("unroll")                                                                  \
            for (int kh = 0; kh < 2; ++kh)                                                     \
                af[i][kh] = *(const bf16x8*)&As[((wr * 4 + i) * 2 + kh) * 512 + lane * 8];      \
        _Pragma("unroll")                                                                      \
        for (int j = 0; j < 2; ++j)                                                            \
            _Pragma("unroll")                                                                  \
            for (int kh = 0; kh < 2; ++kh)                                                     \
                bfr[j][kh] = *(const bf16x8*)&Bs[((wc * 2 + j) * 2 + kh) * 512 + lane * 8];     \
        _Pragma("unroll")                                                                      \
        for (int kh = 0; kh < 2; ++kh)                                                         \
            _Pragma("unroll")                                                                  \
            for (int i = 0; i < 4; ++i)                                                        \
                _Pragma("unroll")                                                              \
                for (int j = 0; j < 2; ++j)                                                    \
                    acc[i][j] = __builtin_amdgcn_mfma_f32_16x16x32_bf16(af[i][kh], bfr[j][kh], \
                                                                        acc[i][j], 0, 0, 0);   \
    }

// --- Epilogue shared text (masked/bf16/csum variant is gemm1; plain is gemm2).
#define EPILOGUE(APPLY_MASK, OUT_BF16, FUSE_CSUM)                                              \
    float colsum[2][2] = {{0.0f, 0.0f}, {0.0f, 0.0f}};                                         \
    _Pragma("unroll")                                                                          \
    for (int i = 0; i < 4; ++i) {                                                              \
        const int r0_ = bm + wr * 64 + i * 16 + kq * 4;                                        \
        _Pragma("unroll")                                                                      \
        for (int j = 0; j < 2; ++j) {                                                          \
            const int c0 = bn + wc * 32 + j * 16 + m16;                                        \
            const float bcol = bias[c0];                                                       \
            _Pragma("unroll")                                                                  \
            for (int r = 0; r < 4; ++r) {                                                      \
                const int row = r0_ + r;                                                       \
                float val = acc[i][j][r] + bcol;                                               \
                if (APPLY_MASK) val = (mask[row] == 0) ? 0.0f : val;                           \
                if (FUSE_CSUM) colsum[i >> 1][j] += val;                                       \
                if (OUT_BF16)                                                                  \
                    ((unsigned short*)Cv)[(size_t)row * En + c0] = f2bf(val);                  \
                else                                                                           \
                    ((float*)Cv)[(size_t)row * En + c0] = val;                                 \
            }                                                                                  \
        }                                                                                      \
    }                                                                                          \
    if (FUSE_CSUM) {                                                                           \
        const int gc0 = 4 * by + 2 * wr;                                                       \
        _Pragma("unroll")                                                                      \
        for (int g = 0; g < 2; ++g)                                                            \
            _Pragma("unroll")                                                                  \
            for (int j = 0; j < 2; ++j) {                                                      \
                float s = colsum[g][j];                                                        \
                s += __shfl_xor(s, 16, 64);                                                    \
                s += __shfl_xor(s, 32, 64);                                                    \
                if (kq == 0)                                                                   \
                    csum[(size_t)(gc0 + g) * En + bn + wc * 32 + j * 16 + m16] = s;            \
            }                                                                                  \
    }

// ---------------------------------------------------------------------------
// gemm1: fp32-staged A=x, B=Wv; mask + bf16 out + fused csum.
// 24 named float4 staging regs (2 sets x 12); launch_bounds(256,2) pins
// VGPR <= 256 so 2 blocks/CU occupancy is preserved.
// ---------------------------------------------------------------------------
#define LOADF(k0, A0, A1, A2, A3, A4, A5, B0, B1, B2, B3, B4, B5)                    \
    A0 = *(const float4*)(gA0f + (k0));      B0 = *(const float4*)(gA0f + (k0) + 4); \
    A1 = *(const float4*)(gA0f + (k0) + 32); B1 = *(const float4*)(gA0f + (k0) + 36);\
    A2 = *(const float4*)(gA1f + (k0));      B2 = *(const float4*)(gA1f + (k0) + 4); \
    A3 = *(const float4*)(gA1f + (k0) + 32); B3 = *(const float4*)(gA1f + (k0) + 36);\
    A4 = *(const float4*)(gB0f + (k0));      B4 = *(const float4*)(gB0f + (k0) + 4); \
    A5 = *(const float4*)(gB0f + (k0) + 32); B5 = *(const float4*)(gB0f + (k0) + 36);

#define STOREF(A0, A1, A2, A3, A4, A5, B0, B1, B2, B3, B4, B5) \
    *lA00 = pack8(A0, B0); *lA01 = pack8(A1, B1);              \
    *lA10 = pack8(A2, B2); *lA11 = pack8(A3, B3);              \
    *lB00 = pack8(A4, B4); *lB01 = pack8(A5, B5);

__global__ __launch_bounds__(256, 2)
void gemm1_f32stage(const float* __restrict__ A, const float* __restrict__ Bw,
                    const float* __restrict__ bias, const int* __restrict__ mask,
                    void* __restrict__ Cv, float* __restrict__ csum)
{
    __shared__ __align__(16) unsigned short As[128 * 64];  // 16 KB
    __shared__ __align__(16) unsigned short Bs[64 * 64];   // 8 KB

    const int tid  = threadIdx.x;
    const int lane = tid & 63;
    const int wv   = tid >> 6;
    const int wr   = wv >> 1;
    const int wc   = wv & 1;
    const int id   = blockIdx.y * 16 + blockIdx.x;
    const int xcd  = id & 7;
    const int slot = id >> 3;
    const int by   = xcd * 4 + (slot >> 4);
    const int bx   = slot & 15;
    const int bm   = by * 128;
    const int bn   = bx * 64;
    const int m16  = lane & 15;
    const int kq   = lane >> 4;

    f32x4 acc[4][2] = {};

    const int rg0 = 2 * wv, rg1 = 2 * wv + 1;
    const float* gA0f = A  + (size_t)(bm + 16 * rg0 + m16) * En + kq * 8;
    const float* gA1f = A  + (size_t)(bm + 16 * rg1 + m16) * En + kq * 8;
    const float* gB0f = Bw + (size_t)(bn + 16 * wv  + m16) * En + kq * 8;
    uint4* lA00 = (uint4*)&As[(rg0 * 2 + 0) * 512 + lane * 8];
    uint4* lA01 = (uint4*)&As[(rg0 * 2 + 1) * 512 + lane * 8];
    uint4* lA10 = (uint4*)&As[(rg1 * 2 + 0) * 512 + lane * 8];
    uint4* lA11 = (uint4*)&As[(rg1 * 2 + 1) * 512 + lane * 8];
    uint4* lB00 = (uint4*)&Bs[(wv  * 2 + 0) * 512 + lane * 8];
    uint4* lB01 = (uint4*)&Bs[(wv  * 2 + 1) * 512 + lane * 8];

    // 24 individually named staging registers (arrays spill — R6 lesson).
    float4 pa0, pa1, pa2, pa3, pa4, pa5, pb0, pb1, pb2, pb3, pb4, pb5;
    float4 qa0, qa1, qa2, qa3, qa4, qa5, qb0, qb1, qb2, qb3, qb4, qb5;

    LOADF(0, pa0, pa1, pa2, pa3, pa4, pa5, pb0, pb1, pb2, pb3, pb4, pb5);
    // K=1024, BK=64 -> 16 K-steps, 2x unrolled (alternating reg sets).
#pragma unroll 1
    for (int it = 0; it < 8; ++it) {
        const int kbase = it * 128;
        __syncthreads();                    // prev compute's LDS reads done
        STOREF(pa0, pa1, pa2, pa3, pa4, pa5, pb0, pb1, pb2, pb3, pb4, pb5);
        __syncthreads();                    // writes visible
        LOADF(kbase + 64, qa0, qa1, qa2, qa3, qa4, qa5, qb0, qb1, qb2, qb3, qb4, qb5);
        COMPUTE();

        __syncthreads();
        STOREF(qa0, qa1, qa2, qa3, qa4, qa5, qb0, qb1, qb2, qb3, qb4, qb5);
        __syncthreads();
        if (it < 7) {
            LOADF(kbase + 128, pa0, pa1, pa2, pa3, pa4, pa5, pb0, pb1, pb2, pb3, pb4, pb5);
        }
        COMPUTE();
    }

    EPILOGUE(true, true, true)
}

// ---------------------------------------------------------------------------
// gemm2: bf16-staged (opreb, Wob) — R13 structure, 12 uint4 staging regs.
// ---------------------------------------------------------------------------
#define LOAD6(k0, r0, r1, r2, r3, r4, r5)            \
    r0 = *(const uint4*)(gA0 + (k0));                \
    r1 = *(const uint4*)(gA0 + (k0) + 32);           \
    r2 = *(const uint4*)(gA1 + (k0));                \
    r3 = *(const uint4*)(gA1 + (k0) + 32);           \
    r4 = *(const uint4*)(gB0 + (k0));                \
    r5 = *(const uint4*)(gB0 + (k0) + 32);

#define STORE6(r0, r1, r2, r3, r4, r5)               \
    *lA00 = r0; *lA01 = r1;                          \
    *lA10 = r2; *lA11 = r3;                          \
    *lB00 = r4; *lB01 = r5;

__global__ __launch_bounds__(256)
void gemm2_bf16(const unsigned short* __restrict__ A, const unsigned short* __restrict__ Bw,
                const float* __restrict__ bias, const int* __restrict__ mask,
                void* __restrict__ Cv, float* __restrict__ csum)
{
    __shared__ __align__(16) unsigned short As[128 * 64];  // 16 KB
    __shared__ __align__(16) unsigned short Bs[64 * 64];   // 8 KB

    const int tid  = threadIdx.x;
    const int lane = tid & 63;
    const int wv   = tid >> 6;
    const int wr   = wv >> 1;
    const int wc   = wv & 1;
    const int id   = blockIdx.y * 16 + blockIdx.x;
    const int xcd  = id & 7;
    const int slot = id >> 3;
    const int by   = xcd * 4 + (slot >> 4);
    const int bx   = slot & 15;
    const int bm   = by * 128;
    const int bn   = bx * 64;
    const int m16  = lane & 15;
    const int kq   = lane >> 4;

    f32x4 acc[4][2] = {};

    const int rg0 = 2 * wv, rg1 = 2 * wv + 1;
    const unsigned short* gA0 = A  + (size_t)(bm + 16 * rg0 + m16) * En + kq * 8;
    const unsigned short* gA1 = A  + (size_t)(bm + 16 * rg1 + m16) * En + kq * 8;
    const unsigned short* gB0 = Bw + (size_t)(bn + 16 * wv  + m16) * En + kq * 8;
    uint4* lA00 = (uint4*)&As[(rg0 * 2 + 0) * 512 + lane * 8];
    uint4* lA01 = (uint4*)&As[(rg0 * 2 + 1) * 512 + lane * 8];
    uint4* lA10 = (uint4*)&As[(rg1 * 2 + 0) * 512 + lane * 8];
    uint4* lA11 = (uint4*)&As[(rg1 * 2 + 1) * 512 + lane * 8];
    uint4* lB00 = (uint4*)&Bs[(wv  * 2 + 0) * 512 + lane * 8];
    uint4* lB01 = (uint4*)&Bs[(wv  * 2 + 1) * 512 + lane * 8];

    uint4 p0, p1, p2, p3, p4, p5;
    uint4 q0, q1, q2, q3, q4, q5;

    LOAD6(0, p0, p1, p2, p3, p4, p5);
#pragma unroll 1
    for (int it = 0; it < 8; ++it) {
        const int kbase = it * 128;
        __syncthreads();
        STORE6(p0, p1, p2, p3, p4, p5);
        __syncthreads();
        LOAD6(kbase + 64, q0, q1, q2, q3, q4, q5);
        COMPUTE();

        __syncthreads();
        STORE6(q0, q1, q2, q3, q4, q5);
        __syncthreads();
        if (it < 7) { LOAD6(kbase + 128, p0, p1, p2, p3, p4, p5); }
        COMPUTE();
    }

    EPILOGUE(false, false, false)
}

// ---------------------------------------------------------------------------
// combine: Wo fp32->bf16 cast (issued first, hides in the scan stalls) +
// inline exclusive scan of csum (64 chunk sums per column) + within-chunk
// prefix + weighted combine -> opre (bf16).
// out_pre[b,i,e] = (w2*Pref[i&~1] + (i odd)*w1*vm[i-1] + w0*(T - Pref[i])) / Z
// Z = (i&~1)*w2 + (i odd)*w1 + (S-i)*w0 + 1e-8   (pre-mask normalization)
// Grid (4, 64, 2) = 512 blocks = 2/CU, serial depth 32. Chunk starts even,
// so odd-i prev is always in-chunk. gemm2 (reads Wob) launches after us.
// ---------------------------------------------------------------------------
__global__ __launch_bounds__(256)
void combine(const unsigned short* __restrict__ vm, const float* __restrict__ csum,
             const float* __restrict__ hier, const float* __restrict__ Wo,
             unsigned short* __restrict__ Wob, unsigned short* __restrict__ opre)
{
    // --- Wo cast slice: 512 blocks x 256 threads x 8 elems = 1M elements.
    {
        const int fid = (blockIdx.z * 64 + blockIdx.y) * 4 + blockIdx.x;  // 0..511
        const int base = fid * 2048 + threadIdx.x * 4;                    // first half
#pragma unroll
        for (int half = 0; half < 2; ++half) {
            const int off = base + half * 1024;
            const float4 v = *(const float4*)(Wo + off);
            ushort4 o;
            o.x = f2bf(v.x); o.y = f2bf(v.y); o.z = f2bf(v.z); o.w = f2bf(v.w);
            *(ushort4*)(Wob + off) = o;
        }
    }

    const int e = blockIdx.x * 256 + threadIdx.x;
    const int c = blockIdx.y;     // chunk within batch, 0..63
    const int b = blockIdx.z;
    const int h = e >> 6;   // dh = 64

    const float w0 = hier[((size_t)b * Hn + h) * 3 + 0];
    const float w1 = hier[((size_t)b * Hn + h) * 3 + 1] * 0.5f;
    const float w2 = hier[((size_t)b * Hn + h) * 3 + 2] * 0.25f;

    // Inline exclusive scan over this batch's 64 chunk sums (L2-hot, 512 KB).
    float run = 0.0f, T = 0.0f;
    const int g0 = b * NCH;
    for (int c2 = 0; c2 < NCH; ++c2) {
        const float v = csum[(size_t)(g0 + c2) * En + e];
        if (c2 < c) run += v;
        T += v;
    }

    float prev = 0.0f;
    const size_t base = ((size_t)b * Sn + c * CHUNK) * En + e;

    for (int t = 0; t < CHUNK; ++t) {
        const int i = c * CHUNK + t;
        const float cur = bf2f(vm[base + (size_t)t * En]);
        float num, Z;
        if (i & 1) {
            num = w2 * (run - prev) + w1 * prev + w0 * (T - run);
            Z = (float)(i - 1) * w2 + w1 + (float)(Sn - i) * w0 + 1e-8f;
        } else {
            num = w2 * run + w0 * (T - run);
            Z = (float)i * w2 + (float)(Sn - i) * w0 + 1e-8f;
        }
        opre[base + (size_t)t * En] = f2bf(num / Z);
        run += cur;
        prev = cur;
    }
}

// ---------------------------------------------------------------------------
extern "C" void kernel_launch(void* const* d_in, const int* in_sizes, int n_in,
                              void* d_out, int out_size, void* d_ws, size_t ws_size,
                              hipStream_t stream)
{
    // 0:x 1:attention_mask 2:level_indices 3:Wq 4:bq 5:Wk 6:bk 7:Wv 8:bv 9:hier 10:Wo 11:bo
    const float* x    = (const float*)d_in[0];
    const int*   mask = (const int*)d_in[1];
    const float* Wv   = (const float*)d_in[7];
    const float* bv   = (const float*)d_in[8];
    const float* hier = (const float*)d_in[9];
    const float* Wo   = (const float*)d_in[10];
    const float* bo   = (const float*)d_in[11];
    float* out = (float*)d_out;

    char* ws = (char*)d_ws;
    unsigned short* Wob   = (unsigned short*)ws;  ws += (size_t)En * En * 2;     // 2 MB
    unsigned short* vmb   = (unsigned short*)ws;  ws += (size_t)Mtot * En * 2;   // 8 MB
    float*          csum  = (float*)ws;           ws += (size_t)GCH * En * 4;    // 512 KB
    unsigned short* opreb = (unsigned short*)ws;  ws += (size_t)Mtot * En * 2;   // 8 MB

    dim3 threads(256);
    dim3 gemm_grid(16, 32);   // 512 blocks = 2/CU (XCD-swizzled in-kernel)

    // 1) vm = mask ? (x @ Wv.T + bv) : 0 (bf16) + fused 32-row chunk col sums
    //    (stages directly from fp32 x/Wv — no separate cast dispatch)
    gemm1_f32stage<<<gemm_grid, threads, 0, stream>>>(x, Wv, bv, mask, vmb, csum);
    // 2) Wo cast + weighted combine (inline csum scan) -> opre (bf16)
    combine<<<dim3(En / 256, NCH, Bn), threads, 0, stream>>>(vmb, csum, hier, Wo, Wob, opreb);
    // 3) out = opre @ Wo.T + bo (fp32 out)
    gemm2_bf16<<<gemm_grid, threads, 0, stream>>>(opreb, Wob, bo, nullptr, out, nullptr);
}

// Round 3
// 163.510 us; speedup vs baseline: 1.1336x; 1.1336x over previous
//
#include <hip/hip_runtime.h>
#include <cstdint>
#include <cstddef>

// Problem constants (B, S, E, H, MAXLEN) = (2, 2048, 1024, 16, 2048)
constexpr int Sn = 2048;
constexpr int En = 1024;
constexpr int Bn = 2;
constexpr int Hn = 16;
constexpr int CHUNK = 32;          // 32-row chunks (2 per wave tile)
constexpr int NCH = Sn / CHUNK;    // 64 chunks per batch
constexpr int Mtot = Bn * Sn;      // 4096
constexpr int GCH = Mtot / CHUNK;  // 128 global chunks

typedef __bf16 bf16x8 __attribute__((ext_vector_type(8)));
typedef float  f32x4  __attribute__((ext_vector_type(4)));

__device__ __forceinline__ unsigned short f2bf(float f) {
    union { float f; uint32_t u; } v; v.f = f;
    const uint32_t u = v.u;
    return (unsigned short)((u + 0x7fffu + ((u >> 16) & 1u)) >> 16);  // RNE
}
__device__ __forceinline__ float bf2f(unsigned short s) {
    union { uint32_t u; float f; } v; v.u = (uint32_t)s << 16; return v.f;
}

// ---------------------------------------------------------------------------
// Fused fp32 -> bf16 cast of x (XN) and Wv (WN) in one launch.
// [R15 lesson: staging gemm1 directly from fp32 cost +16 µs (56.2 µs, MfmaUtil
// 5.6%) — doubled staged bytes + 12-vs-6 vmem insts per set lengthen the
// stall chain in this latency-bound structure. Separate cast is cheaper.]
// ---------------------------------------------------------------------------
constexpr int XN = Bn * Sn * En;   // 4194304
constexpr int WN = En * En;        // 1048576

__global__ __launch_bounds__(256)
void cast2(const float* __restrict__ x, const float* __restrict__ Wv,
           unsigned short* __restrict__ xb, unsigned short* __restrict__ Wvb)
{
    const int i = (blockIdx.x * 256 + threadIdx.x) * 4;
    const float* src; unsigned short* dst; int off;
    if (i < XN) { src = x;  dst = xb;  off = i; }
    else        { src = Wv; dst = Wvb; off = i - XN; }
    const float4 v = *(const float4*)(src + off);
    ushort4 o;
    o.x = f2bf(v.x); o.y = f2bf(v.y); o.z = f2bf(v.z); o.w = f2bf(v.w);
    *(ushort4*)(dst + off) = o;
}

// ---------------------------------------------------------------------------
// bf16 MFMA GEMM (NT) — R13 structure (best measured: 166 µs total).
// C[m,n] = sum_k A[m,k]*W[n,k] + bias[n].
// Tile 128(M) x 64(N), BK=64, 256 threads = 4 waves in 2x2, wave tile 64x32.
// Staging: global -> 12 named uint4 VGPRs -> ds_write_b128. LDS: 1024 B
// chunk = 16 rows x 32 k in fragment order, lane l -> slot l*16 B
// (conflict-free b128). XCD swizzle: xcd = id&7 owns 4 contiguous
// row-blocks (A 1 MB + B 2 MB < 4 MB per-XCD L2).
// [Measured R2: this family at this shape is latency-bound — MfmaUtil ~6%,
// VALUBusy ~7%, HBM ~8%, occupancy ~20%. Session's six K-loop structures
// and R14's 3-deep staging all ~40 µs/GEMM. Plateau is structural (m233:
// 2-phase stage+barrier = ~72% stall); do not spend more rounds inside it
// without an 8-phase-style restructure.]
// ---------------------------------------------------------------------------
#define LOAD6(k0, r0, r1, r2, r3, r4, r5)            \
    r0 = *(const uint4*)(gA0 + (k0));                \
    r1 = *(const uint4*)(gA0 + (k0) + 32);           \
    r2 = *(const uint4*)(gA1 + (k0));                \
    r3 = *(const uint4*)(gA1 + (k0) + 32);           \
    r4 = *(const uint4*)(gB0 + (k0));                \
    r5 = *(const uint4*)(gB0 + (k0) + 32);

#define STORE6(r0, r1, r2, r3, r4, r5)               \
    *lA00 = r0; *lA01 = r1;                          \
    *lA10 = r2; *lA11 = r3;                          \
    *lB00 = r4; *lB01 = r5;

#define COMPUTE()                                                                              \
    {                                                                                          \
        bf16x8 af[4][2], bfr[2][2];                                                            \
        _Pragma("unroll")                                                                      \
        for (int i = 0; i < 4; ++i)                                                            \
            _Pragma("unroll")                                                                  \
            for (int kh = 0; kh < 2; ++kh)                                                     \
                af[i][kh] = *(const bf16x8*)&As[((wr * 4 + i) * 2 + kh) * 512 + lane * 8];      \
        _Pragma("unroll")                                                                      \
        for (int j = 0; j < 2; ++j)                                                            \
            _Pragma("unroll")                                                                  \
            for (int kh = 0; kh < 2; ++kh)                                                     \
                bfr[j][kh] = *(const bf16x8*)&Bs[((wc * 2 + j) * 2 + kh) * 512 + lane * 8];     \
        _Pragma("unroll")                                                                      \
        for (int kh = 0; kh < 2; ++kh)                                                         \
            _Pragma("unroll")                                                                  \
            for (int i = 0; i < 4; ++i)                                                        \
                _Pragma("unroll")                                                              \
                for (int j = 0; j < 2; ++j)                                                    \
                    acc[i][j] = __builtin_amdgcn_mfma_f32_16x16x32_bf16(af[i][kh], bfr[j][kh], \
                                                                        acc[i][j], 0, 0, 0);   \
    }

template<bool APPLY_MASK, bool OUT_BF16, bool FUSE_CSUM>
__global__ __launch_bounds__(256)
void gemm_pipe(const unsigned short* __restrict__ A, const unsigned short* __restrict__ Bw,
               const float* __restrict__ bias, const int* __restrict__ mask,
               void* __restrict__ Cv, float* __restrict__ csum)
{
    __shared__ __align__(16) unsigned short As[128 * 64];  // 16 KB
    __shared__ __align__(16) unsigned short Bs[64 * 64];   // 8 KB

    const int tid  = threadIdx.x;
    const int lane = tid & 63;
    const int wv   = tid >> 6;      // wave 0..3
    const int wr   = wv >> 1;       // wave row (0..1) -> M
    const int wc   = wv & 1;        // wave col (0..1) -> N
    // XCD-aware swizzle (grid (16, 32)).
    const int id   = blockIdx.y * 16 + blockIdx.x;
    const int xcd  = id & 7;
    const int slot = id >> 3;
    const int by   = xcd * 4 + (slot >> 4);
    const int bx   = slot & 15;
    const int bm   = by * 128;
    const int bn   = bx * 64;
    const int m16  = lane & 15;
    const int kq   = lane >> 4;     // k-quarter (staging) / row-quad (C/D)

    f32x4 acc[4][2] = {};

    const int rg0 = 2 * wv, rg1 = 2 * wv + 1;
    const unsigned short* gA0 = A  + (size_t)(bm + 16 * rg0 + m16) * En + kq * 8;
    const unsigned short* gA1 = A  + (size_t)(bm + 16 * rg1 + m16) * En + kq * 8;
    const unsigned short* gB0 = Bw + (size_t)(bn + 16 * wv  + m16) * En + kq * 8;
    uint4* lA00 = (uint4*)&As[(rg0 * 2 + 0) * 512 + lane * 8];
    uint4* lA01 = (uint4*)&As[(rg0 * 2 + 1) * 512 + lane * 8];
    uint4* lA10 = (uint4*)&As[(rg1 * 2 + 0) * 512 + lane * 8];
    uint4* lA11 = (uint4*)&As[(rg1 * 2 + 1) * 512 + lane * 8];
    uint4* lB00 = (uint4*)&Bs[(wv  * 2 + 0) * 512 + lane * 8];
    uint4* lB01 = (uint4*)&Bs[(wv  * 2 + 1) * 512 + lane * 8];

    // 12 individually named staging registers (arrays spill — R6 lesson).
    uint4 p0, p1, p2, p3, p4, p5;
    uint4 q0, q1, q2, q3, q4, q5;

    LOAD6(0, p0, p1, p2, p3, p4, p5);
    // K=1024, BK=64 -> 16 iterations, 2x unrolled (alternating reg sets).
#pragma unroll 1
    for (int it = 0; it < 8; ++it) {
        const int kbase = it * 128;
        __syncthreads();                        // prev compute's LDS reads done
        STORE6(p0, p1, p2, p3, p4, p5);         // waits vmcnt for p (1 iter old)
        __syncthreads();                        // writes visible
        LOAD6(kbase + 64, q0, q1, q2, q3, q4, q5);   // in flight across MFMAs
        COMPUTE();

        __syncthreads();
        STORE6(q0, q1, q2, q3, q4, q5);
        __syncthreads();
        if (it < 7) { LOAD6(kbase + 128, p0, p1, p2, p3, p4, p5); }
        COMPUTE();
    }

    // Epilogue. C/D layout: col = lane&15, row = (lane>>4)*4 + reg.
    // colsum[g][j]: g = 32-row half of the wave tile, j = 16-col group.
    float colsum[2][2] = {{0.0f, 0.0f}, {0.0f, 0.0f}};
#pragma unroll
    for (int i = 0; i < 4; ++i) {
        const int r0 = bm + wr * 64 + i * 16 + kq * 4;
#pragma unroll
        for (int j = 0; j < 2; ++j) {
            const int c0 = bn + wc * 32 + j * 16 + m16;
            const float bcol = bias[c0];
#pragma unroll
            for (int r = 0; r < 4; ++r) {
                const int row = r0 + r;
                float val = acc[i][j][r] + bcol;
                if (APPLY_MASK) val = (mask[row] == 0) ? 0.0f : val;
                if (FUSE_CSUM) colsum[i >> 1][j] += val;
                if (OUT_BF16)
                    ((unsigned short*)Cv)[(size_t)row * En + c0] = f2bf(val);
                else
                    ((float*)Cv)[(size_t)row * En + c0] = val;
            }
        }
    }

    if (FUSE_CSUM) {
        // Wave wr's 64 rows = global chunks {4*by + 2*wr, +1} (CHUNK=32).
        const int gc0 = 4 * by + 2 * wr;
#pragma unroll
        for (int g = 0; g < 2; ++g)
#pragma unroll
            for (int j = 0; j < 2; ++j) {
                float s = colsum[g][j];
                s += __shfl_xor(s, 16, 64);
                s += __shfl_xor(s, 32, 64);
                if (kq == 0)
                    csum[(size_t)(gc0 + g) * En + bn + wc * 32 + j * 16 + m16] = s;
            }
    }
}

// ---------------------------------------------------------------------------
// combine (R16 rework): Wo cast slice + LDS-staged vm tile + pipelined csum
// scan + weighted combine -> opre (bf16).
//   out_pre[b,i,e] = (w2*Pref[i&~1] + (i odd)*w1*vm[i-1] + w0*(T-Pref[i]))/Z
//   Z = (i&~1)*w2 + (i odd)*w1 + (S-i)*w0 + 1e-8
// Previous version: inner loop = 32-deep serial chain of scalar strided
// global bf16 loads (2 B/lane, ~200-900 cyc each) -> suspected ~35-45 µs.
// Now: (1) issue 4x b128 coalesced loads staging the 32x256 vm tile to LDS
// FIRST (latency hides under csum pass), (2) csum pass unrolled x16 so its
// 64 independent 4B coalesced loads pipeline, (3) serial recurrence reads
// LDS (row-broadcast 2-way bank access = free, m136).
// Grid (4, 64, 2) = 512 blocks = 2/CU. Chunk starts even, so odd-i prev is
// always in-chunk. gemm2 (reads Wob) launches after us.
// ---------------------------------------------------------------------------
__global__ __launch_bounds__(256)
void combine(const unsigned short* __restrict__ vm, const float* __restrict__ csum,
             const float* __restrict__ hier, const float* __restrict__ Wo,
             unsigned short* __restrict__ Wob, unsigned short* __restrict__ opre)
{
    __shared__ __align__(16) unsigned short tile[CHUNK * 256];  // 16 KB

    const int tid = threadIdx.x;
    const int ec0 = blockIdx.x * 256;
    const int c   = blockIdx.y;     // chunk within batch, 0..63
    const int b   = blockIdx.z;

    // --- Stage 32x256 vm tile -> LDS: 4 passes x (8 rows x 32 lanes x 16 B).
    {
        const int lane16 = tid & 31;          // 16B segment within a row
        const int rbase  = tid >> 5;          // 0..7
        const size_t g0 = ((size_t)b * Sn + c * CHUNK) * En + ec0 + lane16 * 8;
#pragma unroll
        for (int r4 = 0; r4 < 4; ++r4) {
            const int row = r4 * 8 + rbase;
            *(uint4*)&tile[row * 256 + lane16 * 8] =
                *(const uint4*)(vm + g0 + (size_t)row * En);
        }
    }

    // --- Wo cast slice: 512 blocks x 256 threads x 8 elems = 1M elements.
    {
        const int fid = (blockIdx.z * 64 + blockIdx.y) * 4 + blockIdx.x;  // 0..511
        const int base = fid * 2048 + tid * 4;
#pragma unroll
        for (int half = 0; half < 2; ++half) {
            const int off = base + half * 1024;
            const float4 v = *(const float4*)(Wo + off);
            ushort4 o;
            o.x = f2bf(v.x); o.y = f2bf(v.y); o.z = f2bf(v.z); o.w = f2bf(v.w);
            *(ushort4*)(Wob + off) = o;
        }
    }

    const int e = ec0 + tid;
    const int h = e >> 6;   // dh = 64
    const float w0 = hier[((size_t)b * Hn + h) * 3 + 0];
    const float w1 = hier[((size_t)b * Hn + h) * 3 + 1] * 0.5f;
    const float w2 = hier[((size_t)b * Hn + h) * 3 + 2] * 0.25f;

    // --- Exclusive scan over this batch's 64 chunk sums (coalesced, x16
    //     unrolled so loads cluster; c is block-uniform -> branchless add).
    float run = 0.0f, T = 0.0f;
    {
        const float* cp = csum + (size_t)b * NCH * En + e;
#pragma unroll 16
        for (int c2 = 0; c2 < NCH; ++c2) {
            const float v = cp[(size_t)c2 * En];
            T += v;
            run += (c2 < c) ? v : 0.0f;
        }
    }

    __syncthreads();   // vm tile visible

    float prev = 0.0f;
    const size_t base = ((size_t)b * Sn + c * CHUNK) * En + e;

#pragma unroll
    for (int t = 0; t < CHUNK; ++t) {
        const int i = c * CHUNK + t;
        const float cur = bf2f(tile[t * 256 + tid]);
        float num, Z;
        if (i & 1) {
            num = w2 * (run - prev) + w1 * prev + w0 * (T - run);
            Z = (float)(i - 1) * w2 + w1 + (float)(Sn - i) * w0 + 1e-8f;
        } else {
            num = w2 * run + w0 * (T - run);
            Z = (float)i * w2 + (float)(Sn - i) * w0 + 1e-8f;
        }
        opre[base + (size_t)t * En] = f2bf(num / Z);
        run += cur;
        prev = cur;
    }
}

// ---------------------------------------------------------------------------
extern "C" void kernel_launch(void* const* d_in, const int* in_sizes, int n_in,
                              void* d_out, int out_size, void* d_ws, size_t ws_size,
                              hipStream_t stream)
{
    // 0:x 1:attention_mask 2:level_indices 3:Wq 4:bq 5:Wk 6:bk 7:Wv 8:bv 9:hier 10:Wo 11:bo
    const float* x    = (const float*)d_in[0];
    const int*   mask = (const int*)d_in[1];
    const float* Wv   = (const float*)d_in[7];
    const float* bv   = (const float*)d_in[8];
    const float* hier = (const float*)d_in[9];
    const float* Wo   = (const float*)d_in[10];
    const float* bo   = (const float*)d_in[11];
    float* out = (float*)d_out;

    char* ws = (char*)d_ws;
    unsigned short* xb    = (unsigned short*)ws;  ws += (size_t)Mtot * En * 2;   // 8 MB
    unsigned short* Wvb   = (unsigned short*)ws;  ws += (size_t)En * En * 2;     // 2 MB
    unsigned short* Wob   = (unsigned short*)ws;  ws += (size_t)En * En * 2;     // 2 MB
    unsigned short* vmb   = (unsigned short*)ws;  ws += (size_t)Mtot * En * 2;   // 8 MB
    float*          csum  = (float*)ws;           ws += (size_t)GCH * En * 4;    // 512 KB
    unsigned short* opreb = (unsigned short*)ws;  ws += (size_t)Mtot * En * 2;   // 8 MB

    dim3 threads(256);

    // Casts to bf16: x + Wv only (Wo is cast inside combine, pre-gemm2)
    cast2<<<dim3((XN + WN) / 1024), threads, 0, stream>>>(x, Wv, xb, Wvb);

    dim3 gemm_grid(16, 32);   // 512 blocks = 2/CU (XCD-swizzled in-kernel)

    // 1) vm = mask ? (x @ Wv.T + bv) : 0 (bf16) + fused 32-row chunk col sums
    gemm_pipe<true, true, true><<<gemm_grid, threads, 0, stream>>>(xb, Wvb, bv, mask, vmb, csum);
    // 2) Wo cast + LDS-staged weighted combine (inline csum scan) -> opre (bf16)
    combine<<<dim3(En / 256, NCH, Bn), threads, 0, stream>>>(vmb, csum, hier, Wo, Wob, opreb);
    // 3) out = opre @ Wo.T + bo (fp32 out)
    gemm_pipe<false, false, false><<<gemm_grid, threads, 0, stream>>>(opreb, Wob, bo, nullptr, out, nullptr);
}